// Round 4
// baseline (234.892 us; speedup 1.0000x reference)
//
#include <hip/hip_runtime.h>
#include <math.h>

// Problem constants (from reference)
constexpr int L     = 2048;   // series length
constexpr int NH    = 96;     // forecast horizon / W cols
constexpr int MLEN  = 150;    // AR2 fit window
constexpr int NAR   = 148;    // number of AR2 regression terms
constexpr float LAM    = 0.001f;
constexpr float CLIP_K = 4.0f;

constexpr int TM    = 32;     // rows per block
constexpr int STEPS = L / 32; // 64 K-steps

typedef __attribute__((ext_vector_type(8))) short short8;   // 8 bf16 MFMA A/B frag
typedef __attribute__((ext_vector_type(4))) float floatx4;  // MFMA C/D frag

// fp32 -> bf16 round-to-nearest-even
__device__ inline short f2bf(float f) {
    union { float f; unsigned u; } v; v.f = f;
    unsigned r = v.u + 0x7FFFu + ((v.u >> 16) & 1u);
    return (short)(r >> 16);
}

// Pre-kernel: Wt[n][k] = bf16(W[k][n]); W is 768 KB -> L2-resident gather.
__global__ __launch_bounds__(256) void wt_kernel(
    const float* __restrict__ W, short* __restrict__ Wt)
{
    int idx = blockIdx.x * 256 + threadIdx.x;   // n*2048 + k
    int n = idx >> 11;
    int k = idx & 2047;
    Wt[idx] = f2bf(W[k * NH + n]);
}

// Main kernel: 256 threads = 4 waves per 32-row tile, full K per block.
// Wave w: row-half h=w>>1 (rows h*16..h*16+15), col-group g=w&1 (j in 3g..3g+2)
// -> each wave owns a disjoint 16x48 output quarter (no acc reduction).
// A: fp32 staged global->LDS via global_load_lds (16B/lane), double-buffered,
//    16B chunks XOR-swizzled by (row&7) to kill ds_read_b128 bank conflicts.
// B: bf16 frags from Wt (L2-resident), register prefetch depth 1.
// MFMA layouts: A[m=lane&15][k=quad*8+j]; B[k=quad*8+j][n=lane&15];
// D col=lane&15, row=quad*4+reg.
__global__ __launch_bounds__(256) void gemm_ar2_kernel(
    const float* __restrict__ x, const short* __restrict__ Wt,
    float* __restrict__ out)
{
    __shared__ float As[2][TM * 32];    // [buf][row*32 + k], fp32, swizzled chunks
    __shared__ float Ys[TM][NH + 1];    // +1 pad (stride-97 writes)
    __shared__ float los[TM], his[TM];

    const int t    = threadIdx.x;
    const int lane = t & 63;
    const int wv   = t >> 6;
    const int h    = wv >> 1;          // row half
    const int g    = wv & 1;           // col group
    const int m    = lane & 15;
    const int quad = lane >> 4;
    const int row0 = blockIdx.x * TM;
    const int r    = h * 16 + m;       // local row this lane's frags cover

    // --- staging geometry: wave w stages 8 rows [w*8, w*8+8) per tile ---
    const int sr = wv * 8 + (lane >> 3);        // local row staged by this lane
    const int sc = lane & 7;                    // LDS 16B-chunk slot (= lane dest)
    const int gc = sc ^ (sr & 7);               // swizzled global chunk
    const float* sgptr = x + (size_t)(row0 + sr) * L + gc * 4;

    // --- B base: Wt row 16*(3g+jj)+m, k-contiguous ---
    const short* wbase = Wt + (size_t)(48 * g + m) * L + quad * 8;

    floatx4 acc[3];
    #pragma unroll
    for (int jj = 0; jj < 3; ++jj) acc[jj] = floatx4{0.f, 0.f, 0.f, 0.f};

    float sum = 0.f, sumsq = 0.f;

    // prologue: stage tile 0, preload B frags for step 0
    __builtin_amdgcn_global_load_lds(
        (const __attribute__((address_space(1))) unsigned int*)sgptr,
        (__attribute__((address_space(3))) unsigned int*)&As[0][wv * 256],
        16, 0, 0);
    short8 b_c[3], b_n[3];
    #pragma unroll
    for (int jj = 0; jj < 3; ++jj)
        b_c[jj] = *(const short8*)(wbase + jj * 16 * L);

    // swizzled LDS read positions for this lane's A frag
    const int p0 = (2 * quad)     ^ (r & 7);
    const int p1 = (2 * quad + 1) ^ (r & 7);

    for (int s = 0; s < STEPS; ++s) {
        const int cur = s & 1;
        __syncthreads();   // As[cur] staged (vmcnt drained at this barrier)

        // stage next A tile into the other buffer (no VGPRs, deep queue)
        if (s + 1 < STEPS)
            __builtin_amdgcn_global_load_lds(
                (const __attribute__((address_space(1))) unsigned int*)(sgptr + (s + 1) * 32),
                (__attribute__((address_space(3))) unsigned int*)&As[cur ^ 1][wv * 256],
                16, 0, 0);

        // prefetch next B frags (L2-hot)
        const int k1 = (s + 1 < STEPS) ? (s + 1) * 32 : s * 32;
        #pragma unroll
        for (int jj = 0; jj < 3; ++jj)
            b_n[jj] = *(const short8*)(wbase + jj * 16 * L + k1);

        // A frag from LDS (fp32), swizzled chunks; bank-conflict-free
        float4 f0 = *(const float4*)(&As[cur][r * 32 + p0 * 4]);
        float4 f1 = *(const float4*)(&As[cur][r * 32 + p1 * 4]);

        // per-row stats: g==0 waves cover all k of their 16 rows via quads
        if (g == 0) {
            sum  += ((f0.x + f0.y) + (f0.z + f0.w))
                  + ((f1.x + f1.y) + (f1.z + f1.w));
            sumsq = fmaf(f0.x, f0.x, sumsq); sumsq = fmaf(f0.y, f0.y, sumsq);
            sumsq = fmaf(f0.z, f0.z, sumsq); sumsq = fmaf(f0.w, f0.w, sumsq);
            sumsq = fmaf(f1.x, f1.x, sumsq); sumsq = fmaf(f1.y, f1.y, sumsq);
            sumsq = fmaf(f1.z, f1.z, sumsq); sumsq = fmaf(f1.w, f1.w, sumsq);
        }

        short8 af;
        af[0] = f2bf(f0.x); af[1] = f2bf(f0.y); af[2] = f2bf(f0.z); af[3] = f2bf(f0.w);
        af[4] = f2bf(f1.x); af[5] = f2bf(f1.y); af[6] = f2bf(f1.z); af[7] = f2bf(f1.w);

        #pragma unroll
        for (int jj = 0; jj < 3; ++jj)
            acc[jj] = __builtin_amdgcn_mfma_f32_16x16x32_bf16(af, b_c[jj], acc[jj], 0, 0, 0);

        #pragma unroll
        for (int jj = 0; jj < 3; ++jj) b_c[jj] = b_n[jj];
    }

    // --- per-row finalize: g==0 waves own rows h*16..h*16+15 ---
    if (g == 0) {
        sum   += __shfl_xor(sum,   16); sum   += __shfl_xor(sum,   32);
        sumsq += __shfl_xor(sumsq, 16); sumsq += __shfl_xor(sumsq, 32);

        // AR2 normal-equation sums over the last-150 tail (cache-hot)
        const float* ytail = x + (size_t)(row0 + r) * L + (L - MLEN);
        float A11 = 0.f, A22 = 0.f, A12 = 0.f, b1 = 0.f, b2 = 0.f;
        for (int i = quad; i < NAR; i += 4) {
            float p2v = ytail[i];
            float p1v = ytail[i + 1];
            float Yv  = ytail[i + 2];
            A11 = fmaf(p1v, p1v, A11);
            A22 = fmaf(p2v, p2v, A22);
            A12 = fmaf(p1v, p2v, A12);
            b1  = fmaf(p1v, Yv,  b1);
            b2  = fmaf(p2v, Yv,  b2);
        }
        A11 += __shfl_xor(A11, 16); A11 += __shfl_xor(A11, 32);
        A22 += __shfl_xor(A22, 16); A22 += __shfl_xor(A22, 32);
        A12 += __shfl_xor(A12, 16); A12 += __shfl_xor(A12, 32);
        b1  += __shfl_xor(b1,  16); b1  += __shfl_xor(b1,  32);
        b2  += __shfl_xor(b2,  16); b2  += __shfl_xor(b2,  32);

        if (quad == 0) {               // 16 lanes: one row each
            A11 += LAM; A22 += LAM;
            float det = A11 * A22 - A12 * A12;
            float a1c = (b1 * A22 - b2 * A12) / det;
            float a2c = (A11 * b2 - A12 * b1) / det;

            float last = ytail[MLEN - 1];
            float y1 = last;
            float y2 = ytail[MLEN - 2];
            for (int n = 0; n < NH; ++n) {
                float yn = a1c * y1 + a2c * y2;
                Ys[r][n] = yn;
                y2 = y1; y1 = yn;
            }
            float var  = (sumsq - sum * sum * (1.0f / L)) * (1.0f / (L - 1));
            float hstd = fmaxf(sqrtf(fmaxf(var, 0.f)), 1e-6f);
            los[r] = last - CLIP_K * hstd;
            his[r] = last + CLIP_K * hstd;
        }
    }
    __syncthreads();

    // --- epilogue: each wave stores its disjoint 16x48 quarter ---
    #pragma unroll
    for (int reg = 0; reg < 4; ++reg) {
        int rl = h * 16 + quad * 4 + reg;
        float lo = los[rl], hi = his[rl];
        #pragma unroll
        for (int jj = 0; jj < 3; ++jj) {
            int c = (3 * g + jj) * 16 + m;
            float v = acc[jj][reg] + Ys[rl][c];
            v = fminf(fmaxf(v, lo), hi);
            out[(size_t)(row0 + rl) * NH + c] = v;
        }
    }
}

extern "C" void kernel_launch(void* const* d_in, const int* in_sizes, int n_in,
                              void* d_out, int out_size, void* d_ws, size_t ws_size,
                              hipStream_t stream) {
    const float* x = (const float*)d_in[0];   // (32,512,2048) fp32
    const float* W = (const float*)d_in[1];   // (2048,96) fp32
    float* out = (float*)d_out;               // (32,512,96) fp32
    short* Wt  = (short*)d_ws;                // 96*2048 bf16 = 384 KB scratch

    wt_kernel<<<dim3((NH * L) / 256), dim3(256), 0, stream>>>(W, Wt);

    const int rows = 32 * 512;                // 16384
    gemm_ar2_kernel<<<dim3(rows / TM), dim3(256), 0, stream>>>(x, Wt, out);
}

// Round 5
// 205.871 us; speedup vs baseline: 1.1410x; 1.1410x over previous
//
#include <hip/hip_runtime.h>
#include <math.h>

// Problem constants (from reference)
constexpr int L     = 2048;
constexpr int NH    = 96;
constexpr int MLEN  = 150;
constexpr int NAR   = 148;
constexpr float LAM    = 0.001f;
constexpr float CLIP_K = 4.0f;

constexpr int TM     = 32;      // rows per block
constexpr int KM     = 64;      // macro K-tile (2 MFMA sub-steps)
constexpr int MSTEPS = L / KM;  // 32

typedef __attribute__((ext_vector_type(8))) short short8;   // 8 bf16 MFMA A/B frag
typedef __attribute__((ext_vector_type(4))) float floatx4;  // MFMA C/D frag

// fp32 -> bf16 round-to-nearest-even
__device__ inline short f2bf(float f) {
    union { float f; unsigned u; } v; v.f = f;
    unsigned r = v.u + 0x7FFFu + ((v.u >> 16) & 1u);
    return (short)(r >> 16);
}

// Pre-kernel: Wt[n][k] = bf16(W[k][n]); 768 KB -> L2-resident gather.
__global__ __launch_bounds__(256) void wt_kernel(
    const float* __restrict__ W, short* __restrict__ Wt)
{
    int idx = blockIdx.x * 256 + threadIdx.x;   // n*2048 + k
    int n = idx >> 11;
    int k = idx & 2047;
    Wt[idx] = f2bf(W[k * NH + n]);
}

// 256 threads = 4 waves per 32-row tile, full K.
// Wave w: row-half h=w>>1 (16 rows), col-half g=w&1 (48 cols) -> disjoint
// 16x48 output quarter, no cross-wave accumulator reduction.
// A: fp32 staged global->LDS (global_load_lds 16B), double-buffered,
//    16B chunks XOR-swizzled by (row&7) within each 128B half-row.
// B: bf16 Wt staged global->LDS once per block per K-tile ([n][k] layout,
//    16B chunks XOR-swizzled by (n&7)) -- dense 128B rows, no per-wave
//    redundant global B reads.
// MFMA layouts: A[m=lane&15][k=quad*8+j]; B[k=quad*8+j][n=lane&15];
// D col=lane&15, row=quad*4+reg.
__global__ __launch_bounds__(256) void gemm_ar2_kernel(
    const float* __restrict__ x, const short* __restrict__ Wt,
    float* __restrict__ out)
{
    __shared__ float As[2][TM * KM];     // 2 x 8 KB fp32
    __shared__ short Bs[2][NH * KM];     // 2 x 12 KB bf16
    __shared__ float Ys[TM][NH + 1];     // +1 pad (stride-97 writes)
    __shared__ float los[TM], his[TM];

    const int t    = threadIdx.x;
    const int lane = t & 63;
    const int wv   = t >> 6;
    const int h    = wv >> 1;
    const int g    = wv & 1;
    const int m    = lane & 15;
    const int quad = lane >> 4;
    const int row0 = blockIdx.x * TM;
    const int r    = h * 16 + m;        // local row of this lane's A frag

    // ---- A staging source (2 instr/wave: chunks c = wv*128 + i*64 + lane) ----
    // c -> row = c>>4 (0..31), ch = c&15; within-row: half h2=ch>>3, pos p=ch&7,
    // global chunk = p ^ (row&7); 16B chunks (4 floats).
    const int cA0 = wv * 128 + lane, cA1 = cA0 + 64;
    const int rA0 = cA0 >> 4, chA0 = cA0 & 15;
    const int rA1 = cA1 >> 4, chA1 = cA1 & 15;
    const float* pa0 = x + (size_t)(row0 + rA0) * L
                         + ((chA0 >> 3) * 32 + ((chA0 & 7) ^ (rA0 & 7)) * 4);
    const float* pa1 = x + (size_t)(row0 + rA1) * L
                         + ((chA1 >> 3) * 32 + ((chA1 & 7) ^ (rA1 & 7)) * 4);

    // ---- B staging source (3 instr/wave: chunks c = wv*192 + j*64 + lane) ----
    // c -> n = c>>3, kc = c&7; source chunk = kc ^ (n&7); 16B chunks (8 bf16).
    const int cB0 = wv * 192 + lane, cB1 = cB0 + 64, cB2 = cB0 + 128;
    const short* pb0 = Wt + (size_t)(cB0 >> 3) * L + (((cB0 & 7) ^ ((cB0 >> 3) & 7)) * 8);
    const short* pb1 = Wt + (size_t)(cB1 >> 3) * L + (((cB1 & 7) ^ ((cB1 >> 3) & 7)) * 8);
    const short* pb2 = Wt + (size_t)(cB2 >> 3) * L + (((cB2 & 7) ^ ((cB2 >> 3) & 7)) * 8);

    floatx4 acc[3];
    #pragma unroll
    for (int jj = 0; jj < 3; ++jj) acc[jj] = floatx4{0.f, 0.f, 0.f, 0.f};
    float sum = 0.f, sumsq = 0.f;

    // swizzled A read chunk positions (r&7 == m&7)
    const int pA0 = (2 * quad)     ^ (m & 7);
    const int pA1 = (2 * quad + 1) ^ (m & 7);

    auto stage = [&](int buf, int k0) {
        __builtin_amdgcn_global_load_lds(
            (const __attribute__((address_space(1))) unsigned int*)(pa0 + k0),
            (__attribute__((address_space(3))) unsigned int*)&As[buf][wv * 512], 16, 0, 0);
        __builtin_amdgcn_global_load_lds(
            (const __attribute__((address_space(1))) unsigned int*)(pa1 + k0),
            (__attribute__((address_space(3))) unsigned int*)&As[buf][wv * 512 + 256], 16, 0, 0);
        __builtin_amdgcn_global_load_lds(
            (const __attribute__((address_space(1))) unsigned int*)(pb0 + k0),
            (__attribute__((address_space(3))) unsigned int*)&Bs[buf][wv * 1536], 16, 0, 0);
        __builtin_amdgcn_global_load_lds(
            (const __attribute__((address_space(1))) unsigned int*)(pb1 + k0),
            (__attribute__((address_space(3))) unsigned int*)&Bs[buf][wv * 1536 + 512], 16, 0, 0);
        __builtin_amdgcn_global_load_lds(
            (const __attribute__((address_space(1))) unsigned int*)(pb2 + k0),
            (__attribute__((address_space(3))) unsigned int*)&Bs[buf][wv * 1536 + 1024], 16, 0, 0);
    };

    stage(0, 0);

    for (int s = 0; s < MSTEPS; ++s) {
        const int cur = s & 1;
        __syncthreads();                       // buf[cur] staged & visible
        if (s + 1 < MSTEPS) stage(cur ^ 1, (s + 1) * KM);

        #pragma unroll
        for (int ss = 0; ss < 2; ++ss) {
            float4 f0 = *(const float4*)&As[cur][r * KM + ss * 32 + pA0 * 4];
            float4 f1 = *(const float4*)&As[cur][r * KM + ss * 32 + pA1 * 4];

            if (g == 0) {   // waves 0,2: full k-coverage of their 16 rows
                sum  += ((f0.x + f0.y) + (f0.z + f0.w))
                      + ((f1.x + f1.y) + (f1.z + f1.w));
                sumsq = fmaf(f0.x, f0.x, sumsq); sumsq = fmaf(f0.y, f0.y, sumsq);
                sumsq = fmaf(f0.z, f0.z, sumsq); sumsq = fmaf(f0.w, f0.w, sumsq);
                sumsq = fmaf(f1.x, f1.x, sumsq); sumsq = fmaf(f1.y, f1.y, sumsq);
                sumsq = fmaf(f1.z, f1.z, sumsq); sumsq = fmaf(f1.w, f1.w, sumsq);
            }

            short8 af;
            af[0] = f2bf(f0.x); af[1] = f2bf(f0.y); af[2] = f2bf(f0.z); af[3] = f2bf(f0.w);
            af[4] = f2bf(f1.x); af[5] = f2bf(f1.y); af[6] = f2bf(f1.z); af[7] = f2bf(f1.w);

            const int bch = ((ss * 4 + quad) ^ (m & 7)) * 8;
            #pragma unroll
            for (int jj = 0; jj < 3; ++jj) {
                short8 bf = *(const short8*)&Bs[cur][(g * 48 + jj * 16 + m) * KM + bch];
                acc[jj] = __builtin_amdgcn_mfma_f32_16x16x32_bf16(af, bf, acc[jj], 0, 0, 0);
            }
        }
    }

    // --- per-row finalize: g==0 waves own rows h*16..h*16+15 ---
    if (g == 0) {
        sum   += __shfl_xor(sum,   16); sum   += __shfl_xor(sum,   32);
        sumsq += __shfl_xor(sumsq, 16); sumsq += __shfl_xor(sumsq, 32);

        const float* ytail = x + (size_t)(row0 + r) * L + (L - MLEN);
        float A11 = 0.f, A22 = 0.f, A12 = 0.f, b1 = 0.f, b2 = 0.f;
        for (int i = quad; i < NAR; i += 4) {
            float p2v = ytail[i];
            float p1v = ytail[i + 1];
            float Yv  = ytail[i + 2];
            A11 = fmaf(p1v, p1v, A11);
            A22 = fmaf(p2v, p2v, A22);
            A12 = fmaf(p1v, p2v, A12);
            b1  = fmaf(p1v, Yv,  b1);
            b2  = fmaf(p2v, Yv,  b2);
        }
        A11 += __shfl_xor(A11, 16); A11 += __shfl_xor(A11, 32);
        A22 += __shfl_xor(A22, 16); A22 += __shfl_xor(A22, 32);
        A12 += __shfl_xor(A12, 16); A12 += __shfl_xor(A12, 32);
        b1  += __shfl_xor(b1,  16); b1  += __shfl_xor(b1,  32);
        b2  += __shfl_xor(b2,  16); b2  += __shfl_xor(b2,  32);

        if (quad == 0) {                // 16 lanes: one row each
            A11 += LAM; A22 += LAM;
            float det = A11 * A22 - A12 * A12;
            float a1c = (b1 * A22 - b2 * A12) / det;
            float a2c = (A11 * b2 - A12 * b1) / det;

            float last = ytail[MLEN - 1];
            float y1 = last;
            float y2 = ytail[MLEN - 2];
            for (int n = 0; n < NH; ++n) {
                float yn = a1c * y1 + a2c * y2;
                Ys[r][n] = yn;
                y2 = y1; y1 = yn;
            }
            float var  = (sumsq - sum * sum * (1.0f / L)) * (1.0f / (L - 1));
            float hstd = fmaxf(sqrtf(fmaxf(var, 0.f)), 1e-6f);
            los[r] = last - CLIP_K * hstd;
            his[r] = last + CLIP_K * hstd;
        }
    }
    __syncthreads();

    // --- epilogue: each wave stores its disjoint 16x48 quarter ---
    #pragma unroll
    for (int reg = 0; reg < 4; ++reg) {
        int rl = h * 16 + quad * 4 + reg;
        float lo = los[rl], hi = his[rl];
        #pragma unroll
        for (int jj = 0; jj < 3; ++jj) {
            int c = (3 * g + jj) * 16 + m;
            float v = acc[jj][reg] + Ys[rl][c];
            v = fminf(fmaxf(v, lo), hi);
            out[(size_t)(row0 + rl) * NH + c] = v;
        }
    }
}

extern "C" void kernel_launch(void* const* d_in, const int* in_sizes, int n_in,
                              void* d_out, int out_size, void* d_ws, size_t ws_size,
                              hipStream_t stream) {
    const float* x = (const float*)d_in[0];   // (32,512,2048) fp32
    const float* W = (const float*)d_in[1];   // (2048,96) fp32
    float* out = (float*)d_out;               // (32,512,96) fp32
    short* Wt  = (short*)d_ws;                // 96*2048 bf16 = 384 KB scratch

    wt_kernel<<<dim3((NH * L) / 256), dim3(256), 0, stream>>>(W, Wt);

    const int rows = 32 * 512;                // 16384
    gemm_ar2_kernel<<<dim3(rows / TM), dim3(256), 0, stream>>>(x, Wt, out);
}